// Round 4
// baseline (1380.069 us; speedup 1.0000x reference)
//
#include <hip/hip_runtime.h>
#include <stdint.h>

#define NB 8
#define NN 2048
#define NU 256
#define CAP 64
#define BNEPS 0.001f

typedef __attribute__((ext_vector_type(8))) short short8;
typedef __attribute__((ext_vector_type(4))) float floatx4;
typedef unsigned short u16;
typedef unsigned int u32;

__device__ __forceinline__ float bf2f(u16 u) {
  union { u32 i; float f; } c; c.i = ((u32)u) << 16; return c.f;
}
__device__ __forceinline__ u16 f2bf(float f) {
  union { float f; u32 i; } c; c.f = f;
  return (u16)((c.i + 0x7fffu + ((c.i >> 16) & 1u)) >> 16);
}
// hi/lo split: a = bf2f(h) + bf2f(l) + O(2^-18 |a|)
__device__ __forceinline__ void splitbf(float a, u16& h, u16& l) {
  h = f2bf(a);
  l = f2bf(a - bf2f(h));
}

enum : unsigned {
  F_AGG = 1u, F_BIAS = 2u, F_SILU = 4u, F_MASKPRE = 8u, F_MASKPOST = 16u,
  F_ADDX = 32u, F_BN = 64u, F_ADDT = 128u, F_ASHARED = 256u, F_BPERMAT = 512u,
  F_TPLANES = 1024u
};

// per-mat transposed plane: 256x2048 u16 = 524288; 8 mats hi, then lo
#define TP_MAT 524288
#define TP_LO  4194304

// ---------------------------------------------------------------------------
// Neighbor-list build: one block per (b, m) row of adj; values are exactly 0/1.
// ---------------------------------------------------------------------------
__global__ __launch_bounds__(256) void build_nbr_k(
    const float* __restrict__ adj, int* __restrict__ cnt, int* __restrict__ idx)
{
  int row = blockIdx.x;  // b*NN + m
  const float* base = adj + (size_t)row * NN;
  __shared__ int c;
  if (threadIdx.x == 0) c = 0;
  __syncthreads();
#pragma unroll
  for (int j = 0; j < 8; j++) {
    int n = j * 256 + threadIdx.x;  // coalesced
    if (base[n] != 0.f) {
      int p = atomicAdd(&c, 1);
      if (p < CAP) idx[(size_t)row * CAP + p] = n;
    }
  }
  __syncthreads();
  if (threadIdx.x == 0) cnt[row] = (c < CAP ? c : CAP);
}

// ---------------------------------------------------------------------------
// Weight conversion: f32 [K=256][N=256] -> TWO bf16 swizzled-B^T planes
// (hi plane [16 mats], then lo plane [16 mats], each mat 65536 u16):
// dst[kb][n][slot][j] = part(W[kb*32 + qv*8 + j][n]), qv = (slot - (n>>1)) & 3
// GEMM reads lane fragment directly from global at n*32 + ((q+(n>>1))&3)*8.
// ---------------------------------------------------------------------------
struct WPtrs { const float* p[16]; };

__global__ __launch_bounds__(256) void conv_w_k(WPtrs wp, u16* __restrict__ dst)
{
  int gid = blockIdx.x * 256 + threadIdx.x;  // 16 mats * 8192 chunks
  int mat = gid >> 13;
  int rem = gid & 8191;
  int kb = rem >> 10;
  int n = (rem >> 2) & 255;
  int slot = rem & 3;
  int qv = (slot - (n >> 1)) & 3;
  int k0 = kb * 32 + qv * 8;
  const float* W = wp.p[mat];
  u32 oh[4], ol[4];
#pragma unroll
  for (int t2 = 0; t2 < 4; t2++) {
    float f0 = W[(size_t)(k0 + 2 * t2) * 256 + n];
    float f1 = W[(size_t)(k0 + 2 * t2 + 1) * 256 + n];
    u16 h0, l0, h1, l1;
    splitbf(f0, h0, l0);
    splitbf(f1, h1, l1);
    oh[t2] = (u32)h0 | ((u32)h1 << 16);
    ol[t2] = (u32)l0 | ((u32)l1 << 16);
  }
  uint4 qh; qh.x = oh[0]; qh.y = oh[1]; qh.z = oh[2]; qh.w = oh[3];
  uint4 ql; ql.x = ol[0]; ql.y = ol[1]; ql.z = ol[2]; ql.w = ol[3];
  *(uint4*)(dst + (size_t)gid * 8) = qh;
  *(uint4*)(dst + 1048576 + (size_t)gid * 8) = ql;  // lo plane at +16*65536
}

// ---------------------------------------------------------------------------
// Workhorse GEMM, fp32-emulated via bf16 hi/lo 3-term MFMA.
// Tile: 16 rows x 256 cols, 256 thr (4 waves x 64 cols).
// A staged+split in LDS (pitch 264, +16B pad) -> 16.9 KB -> 8 blocks/CU.
// B fragments read per-lane DIRECTLY from the swizzled global planes (L2-hot):
// barrier-free K-loop.
// Grid: 1-D 1024*NG, XCD-swizzled: xcd = id&7.
// ---------------------------------------------------------------------------
template <unsigned F, int NG>
__global__ __launch_bounds__(256, 8) void gemm_k(
    const float* __restrict__ Abase,
    const u16* __restrict__ W0, const u16* __restrict__ W1, const u16* __restrict__ W2,
    size_t loOff,
    const float* __restrict__ b0, const float* __restrict__ b1, const float* __restrict__ b2,
    const float* __restrict__ mask,
    const float* __restrict__ xf32,
    const float* __restrict__ gma, const float* __restrict__ bta,
    const float* __restrict__ bmu, const float* __restrict__ bvr,
    const float* __restrict__ addt,
    const int* __restrict__ ncnt, const int* __restrict__ nidx,
    void* __restrict__ outp)
{
  const int tid = threadIdx.x;
  const int id = blockIdx.x;
  const int xcd = id & 7;
  const int t = id >> 3;
  const int chain = (NG == 1) ? 0 : (t % NG);
  const int xt = (NG == 1) ? t : (t / NG);
  const int mat = chain * 8 + xcd;
  const int b = xcd;
  const int bm = xt * 16;

  __shared__ alignas(16) u16 Ah[16 * 264];  // 8448 B
  __shared__ alignas(16) u16 Al[16 * 264];  // 8448 B -> 16896 B total

  const u16* Whi = (F & F_BPERMAT) ? (W0 + (size_t)mat * 65536)
                                   : (chain == 0 ? W0 : (chain == 1 ? W1 : W2));
  const u16* Wlo = Whi + loOff;
  const float* bsel = (chain == 0 ? b0 : (chain == 1 ? b1 : b2));
  const float* Asrc = Abase + ((F & F_ASHARED) ? (size_t)b : (size_t)mat) * (size_t)(NN * NU);

  // ---- stage A tile (16 x 256), fp32 -> hi/lo bf16; one shot, no loop ----
  {
    int r = tid >> 4;
    int c = (tid & 15) << 4;
    float4 a0, a1, a2, a3;
    if (F & F_AGG) {
      a0.x = a0.y = a0.z = a0.w = 0.f; a1 = a0; a2 = a0; a3 = a0;
      int rowid = b * NN + bm + r;
      int cnt = ncnt[rowid];
      const int* __restrict__ ip = nidx + (size_t)rowid * CAP;
      const float* __restrict__ Ab = Asrc + c;
      int e = 0;
      // 4-wide chunks: 16 independent float4 loads in flight
      for (; e + 4 <= cnt; e += 4) {
        int4 i4 = *(const int4*)(ip + e);
        const float4* q0 = (const float4*)(Ab + ((size_t)i4.x << 8));
        const float4* q1 = (const float4*)(Ab + ((size_t)i4.y << 8));
        const float4* q2 = (const float4*)(Ab + ((size_t)i4.z << 8));
        const float4* q3 = (const float4*)(Ab + ((size_t)i4.w << 8));
        float4 u0 = q0[0], u1 = q0[1], u2 = q0[2], u3 = q0[3];
        float4 v0 = q1[0], v1 = q1[1], v2 = q1[2], v3 = q1[3];
        float4 w0 = q2[0], w1 = q2[1], w2 = q2[2], w3 = q2[3];
        float4 z0 = q3[0], z1 = q3[1], z2 = q3[2], z3 = q3[3];
        a0.x += u0.x + v0.x + w0.x + z0.x; a0.y += u0.y + v0.y + w0.y + z0.y;
        a0.z += u0.z + v0.z + w0.z + z0.z; a0.w += u0.w + v0.w + w0.w + z0.w;
        a1.x += u1.x + v1.x + w1.x + z1.x; a1.y += u1.y + v1.y + w1.y + z1.y;
        a1.z += u1.z + v1.z + w1.z + z1.z; a1.w += u1.w + v1.w + w1.w + z1.w;
        a2.x += u2.x + v2.x + w2.x + z2.x; a2.y += u2.y + v2.y + w2.y + z2.y;
        a2.z += u2.z + v2.z + w2.z + z2.z; a2.w += u2.w + v2.w + w2.w + z2.w;
        a3.x += u3.x + v3.x + w3.x + z3.x; a3.y += u3.y + v3.y + w3.y + z3.y;
        a3.z += u3.z + v3.z + w3.z + z3.z; a3.w += u3.w + v3.w + w3.w + z3.w;
      }
      for (; e < cnt; e++) {
        const float4* q0 = (const float4*)(Ab + ((size_t)ip[e] << 8));
        float4 u0 = q0[0], u1 = q0[1], u2 = q0[2], u3 = q0[3];
        a0.x += u0.x; a0.y += u0.y; a0.z += u0.z; a0.w += u0.w;
        a1.x += u1.x; a1.y += u1.y; a1.z += u1.z; a1.w += u1.w;
        a2.x += u2.x; a2.y += u2.y; a2.z += u2.z; a2.w += u2.w;
        a3.x += u3.x; a3.y += u3.y; a3.z += u3.z; a3.w += u3.w;
      }
    } else {
      const float4* fp = (const float4*)(Asrc + (size_t)(bm + r) * NU + c);
      a0 = fp[0]; a1 = fp[1]; a2 = fp[2]; a3 = fp[3];
    }
    float vv[16] = {a0.x, a0.y, a0.z, a0.w, a1.x, a1.y, a1.z, a1.w,
                    a2.x, a2.y, a2.z, a2.w, a3.x, a3.y, a3.z, a3.w};
    u32 hh[8], ll[8];
#pragma unroll
    for (int j = 0; j < 8; j++) {
      u16 h0, l0, h1, l1;
      splitbf(vv[2 * j], h0, l0);
      splitbf(vv[2 * j + 1], h1, l1);
      hh[j] = (u32)h0 | ((u32)h1 << 16);
      ll[j] = (u32)l0 | ((u32)l1 << 16);
    }
    uint4 H0; H0.x = hh[0]; H0.y = hh[1]; H0.z = hh[2]; H0.w = hh[3];
    uint4 H1; H1.x = hh[4]; H1.y = hh[5]; H1.z = hh[6]; H1.w = hh[7];
    uint4 L0; L0.x = ll[0]; L0.y = ll[1]; L0.z = ll[2]; L0.w = ll[3];
    uint4 L1; L1.x = ll[4]; L1.y = ll[5]; L1.z = ll[6]; L1.w = ll[7];
    *(uint4*)&Ah[r * 264 + c] = H0;
    *(uint4*)&Ah[r * 264 + c + 8] = H1;
    *(uint4*)&Al[r * 264 + c] = L0;
    *(uint4*)&Al[r * 264 + c + 8] = L1;
  }
  __syncthreads();

  const int lane = tid & 63;
  const int w = tid >> 6;
  const int m16 = lane & 15;
  const int q = lane >> 4;

  floatx4 acc[4];
#pragma unroll
  for (int j = 0; j < 4; j++) acc[j] = (floatx4){0.f, 0.f, 0.f, 0.f};

  // barrier-free K-loop: B fragments straight from global (swizzled layout)
#pragma unroll
  for (int kk = 0; kk < 8; kk++) {
    short8 ah, al2, bh[4], bl2[4];
#pragma unroll
    for (int nt = 0; nt < 4; nt++) {
      int n = w * 64 + nt * 16 + m16;
      size_t off = (size_t)kk * 8192 + (size_t)n * 32 + (size_t)(((q + (n >> 1)) & 3) * 8);
      bh[nt] = *(const short8*)(Whi + off);
      bl2[nt] = *(const short8*)(Wlo + off);
    }
    ah = *(const short8*)&Ah[m16 * 264 + kk * 32 + q * 8];
    al2 = *(const short8*)&Al[m16 * 264 + kk * 32 + q * 8];
#pragma unroll
    for (int nt = 0; nt < 4; nt++) {
      acc[nt] = __builtin_amdgcn_mfma_f32_16x16x32_bf16(ah, bh[nt], acc[nt], 0, 0, 0);
      acc[nt] = __builtin_amdgcn_mfma_f32_16x16x32_bf16(al2, bh[nt], acc[nt], 0, 0, 0);
      acc[nt] = __builtin_amdgcn_mfma_f32_16x16x32_bf16(ah, bl2[nt], acc[nt], 0, 0, 0);
    }
  }

  // ---- epilogue ----
  if (F & F_TPLANES) {
    // write transposed bf16 hi/lo planes: oT[col][row]
    u16* oh = (u16*)outp + (size_t)b * TP_MAT;
    u16* ol = oh + TP_LO;
    int gr0 = bm + q * 4;
#pragma unroll
    for (int nt = 0; nt < 4; nt++) {
      int col = w * 64 + nt * 16 + m16;
      u16 hh[4], ll[4];
#pragma unroll
      for (int r = 0; r < 4; r++) {
        float t2 = acc[nt][r];
        float mv = mask[b * NN + gr0 + r];
        if (F & F_MASKPRE) t2 *= mv;
        if (F & F_SILU) t2 = t2 / (1.f + __expf(-t2));
        if (F & F_MASKPOST) t2 *= mv;
        splitbf(t2, hh[r], ll[r]);
      }
      uint2 H2, L2v;
      H2.x = (u32)hh[0] | ((u32)hh[1] << 16);
      H2.y = (u32)hh[2] | ((u32)hh[3] << 16);
      L2v.x = (u32)ll[0] | ((u32)ll[1] << 16);
      L2v.y = (u32)ll[2] | ((u32)ll[3] << 16);
      *(uint2*)(oh + (size_t)col * 2048 + gr0) = H2;
      *(uint2*)(ol + (size_t)col * 2048 + gr0) = L2v;
    }
  } else {
    float* outf = (float*)outp;
#pragma unroll
    for (int r = 0; r < 4; r++) {
      int gr = bm + q * 4 + r;
      float mval = 1.f;
      if (F & (F_MASKPRE | F_MASKPOST)) mval = mask[b * NN + gr];
#pragma unroll
      for (int nt = 0; nt < 4; nt++) {
        int col = w * 64 + nt * 16 + m16;
        float t2 = acc[nt][r];
        if (F & F_BIAS) t2 += bsel[col];
        if (F & F_MASKPRE) t2 *= mval;
        if (F & F_SILU) t2 = t2 / (1.f + __expf(-t2));
        if (F & F_ADDX) t2 += xf32[((size_t)b * NN + gr) * NU + col];
        if (F & F_BN) t2 = gma[col] * (t2 - bmu[col]) * rsqrtf(bvr[col] + BNEPS) + bta[col];
        if (F & F_ADDT) t2 += addt[((size_t)mat * NN + gr) * NU + col];
        if (F & F_MASKPOST) t2 *= mval;
        outf[((size_t)mat * NN + gr) * NU + col] = t2;
      }
    }
  }
}

// ---------------------------------------------------------------------------
// kv[d][e] = sum_n pk[n][d] * pv[n][e], from transposed hi/lo planes.
// LDS-free: A/B fragments are direct 16B global loads. Split-K=8:
// part[z = p*8+b][d][e], grid (2,2,64).
// ---------------------------------------------------------------------------
__global__ __launch_bounds__(256, 2) void kv_k(
    const u16* __restrict__ pkT, const u16* __restrict__ pvT, float* __restrict__ part)
{
  int et = blockIdx.x * 128;
  int dt = blockIdx.y * 128;
  int z = blockIdx.z;
  int b = z & 7;
  int p = z >> 3;
  int tid = threadIdx.x;
  int lane = tid & 63, w = tid >> 6;
  int m16 = lane & 15, q = lane >> 4;

  const u16* pkh = pkT + (size_t)b * TP_MAT;
  const u16* pkl = pkh + TP_LO;
  const u16* pvh = pvT + (size_t)b * TP_MAT;
  const u16* pvl = pvh + TP_LO;

  int d_base = dt + (w >> 1) * 64 + m16;
  int e_base = et + (w & 1) * 64 + m16;

  floatx4 acc[4][4];
#pragma unroll
  for (int i = 0; i < 4; i++)
#pragma unroll
    for (int j = 0; j < 4; j++) acc[i][j] = (floatx4){0.f, 0.f, 0.f, 0.f};

#pragma unroll
  for (int kt = 0; kt < 8; kt++) {
    int kc = p * 256 + kt * 32 + q * 8;
    short8 ah[4], al[4], bh[4], bl[4];
#pragma unroll
    for (int mt = 0; mt < 4; mt++) {
      size_t o = (size_t)(d_base + mt * 16) * 2048 + kc;
      ah[mt] = *(const short8*)(pkh + o);
      al[mt] = *(const short8*)(pkl + o);
    }
#pragma unroll
    for (int nt = 0; nt < 4; nt++) {
      size_t o = (size_t)(e_base + nt * 16) * 2048 + kc;
      bh[nt] = *(const short8*)(pvh + o);
      bl[nt] = *(const short8*)(pvl + o);
    }
#pragma unroll
    for (int mt = 0; mt < 4; mt++)
#pragma unroll
      for (int nt = 0; nt < 4; nt++) {
        acc[mt][nt] = __builtin_amdgcn_mfma_f32_16x16x32_bf16(ah[mt], bh[nt], acc[mt][nt], 0, 0, 0);
        acc[mt][nt] = __builtin_amdgcn_mfma_f32_16x16x32_bf16(al[mt], bh[nt], acc[mt][nt], 0, 0, 0);
        acc[mt][nt] = __builtin_amdgcn_mfma_f32_16x16x32_bf16(ah[mt], bl[nt], acc[mt][nt], 0, 0, 0);
      }
  }

#pragma unroll
  for (int mt = 0; mt < 4; mt++)
#pragma unroll
    for (int r = 0; r < 4; r++) {
      int d = dt + (w >> 1) * 64 + mt * 16 + q * 4 + r;
#pragma unroll
      for (int nt = 0; nt < 4; nt++) {
        int e = et + (w & 1) * 64 + nt * 16 + m16;
        part[(size_t)z * 65536 + (size_t)d * 256 + e] = acc[mt][nt][r];
      }
    }
}

// Reduce split-K partials (8 p-planes) and emit kv hi/lo swizzled planes.
__global__ __launch_bounds__(256) void kv_conv_k(const float* __restrict__ part, u16* __restrict__ dst)
{
  int gid = blockIdx.x * 256 + threadIdx.x;  // 8 * 8192 = 65536
  int b = gid >> 13;
  int rem = gid & 8191;
  int kb = rem >> 10;
  int e = (rem >> 2) & 255;
  int slot = rem & 3;
  int qv = (slot - (e >> 1)) & 3;
  int d0 = kb * 32 + qv * 8;
  const float* src = part + (size_t)b * 65536 + (size_t)d0 * 256 + e;
  u32 oh[4], ol[4];
#pragma unroll
  for (int t2 = 0; t2 < 4; t2++) {
    float s0 = 0.f, s1 = 0.f;
#pragma unroll
    for (int pp = 0; pp < 8; pp++) {
      const float* sp = src + (size_t)pp * 524288 + t2 * 512;
      s0 += sp[0];
      s1 += sp[256];
    }
    u16 h0, l0, h1, l1;
    splitbf(s0, h0, l0);
    splitbf(s1, h1, l1);
    oh[t2] = (u32)h0 | ((u32)h1 << 16);
    ol[t2] = (u32)l0 | ((u32)l1 << 16);
  }
  uint4 qh; qh.x = oh[0]; qh.y = oh[1]; qh.z = oh[2]; qh.w = oh[3];
  uint4 ql; ql.x = ol[0]; ql.y = ol[1]; ql.z = ol[2]; ql.w = ol[3];
  *(uint4*)(dst + (size_t)gid * 8) = qh;
  *(uint4*)(dst + 524288 + (size_t)gid * 8) = ql;  // lo plane at +8*65536
}

// ---------------------------------------------------------------------------
extern "C" void kernel_launch(void* const* d_in, const int* in_sizes, int n_in,
                              void* d_out, int out_size, void* d_ws, size_t ws_size,
                              hipStream_t stream)
{
  const float* x = (const float*)d_in[0];
  const float* adj = (const float*)d_in[1];
  const float* mask = (const float*)d_in[2];
  const float* W_lin = (const float*)d_in[3];
  const float* b_lin = (const float*)d_in[4];
  const float* Wq_mp = (const float*)d_in[5];
  const float* bq_mp = (const float*)d_in[6];
  const float* Wk_mp = (const float*)d_in[7];
  const float* bk_mp = (const float*)d_in[8];
  const float* Wv_mp = (const float*)d_in[9];
  const float* bv_mp = (const float*)d_in[10];
  const float* Wk_att = (const float*)d_in[11];
  const float* Wv_att = (const float*)d_in[12];
  const float* Wq_att = (const float*)d_in[13];
  const float* Wo_att = (const float*)d_in[14];
  const float* bn_gamma = (const float*)d_in[15];
  const float* bn_beta = (const float*)d_in[16];
  const float* bn_mean = (const float*)d_in[17];
  const float* bn_var = (const float*)d_in[18];
  const float* W_proj = (const float*)d_in[19];
  const float* b_proj = (const float*)d_in[20];
  const float* W_res = (const float*)d_in[21];
  const float* b_res = (const float*)d_in[22];

  char* ws = (char*)d_ws;
  int* CNT    = (int*)(ws + 0);               // 64 KB
  int* IDX    = (int*)(ws + (1ull << 20));    // 4 MB
  u16* WSZ    = (u16*)(ws + (5ull << 20));    // 4 MB (hi 2MB + lo 2MB)
  u16* KVS    = (u16*)(ws + (9ull << 20));    // 2 MB (hi 1MB + lo 1MB)
  float* KVP  = (float*)(ws + (11ull << 20)); // 16 MB
  float* H    = (float*)(ws + (27ull << 20)); // 16 MB
  float* PING = (float*)(ws + (43ull << 20)); // 48 MB
  float* PONG = (float*)(ws + (91ull << 20)); // 48 MB  (total 139 MB)

  const size_t MSZ = (size_t)NN * NU;
  const size_t WLO = 1048576;  // weight lo-plane offset (u16 elems)
  const size_t KLO = 524288;   // kv lo-plane offset
  u16* PKT = (u16*)PING;                  // 16 MB (hi 8 + lo 8)
  u16* PVT = PKT + 8388608;               // 16 MB
  float* PQ = PING + 16 * MSZ;            // 16 MB
  float* ATTN1 = H;                       // H dead after mp step 0
  float* Y = PONG;                        // q/k/v finals dead after projections
  float* TMP = PING + 8 * MSZ;            // PVT region; dead after kv_k

  // --- conversions + neighbor lists ---
  WPtrs wp;
  wp.p[0] = W_lin;
  wp.p[1] = Wq_mp; wp.p[2] = Wq_mp + 65536; wp.p[3] = Wq_mp + 131072;
  wp.p[4] = Wk_mp; wp.p[5] = Wk_mp + 65536; wp.p[6] = Wk_mp + 131072;
  wp.p[7] = Wv_mp; wp.p[8] = Wv_mp + 65536; wp.p[9] = Wv_mp + 131072;
  wp.p[10] = Wk_att; wp.p[11] = Wv_att; wp.p[12] = Wq_att; wp.p[13] = Wo_att;
  wp.p[14] = W_proj; wp.p[15] = W_res;
  conv_w_k<<<512, 256, 0, stream>>>(wp, WSZ);
  build_nbr_k<<<NB * NN, 256, 0, stream>>>(adj, CNT, IDX);

  // --- h = x @ W_lin + b_lin ---
  gemm_k<F_BIAS, 1><<<1024, 256, 0, stream>>>(x, WSZ, nullptr, nullptr, WLO,
      b_lin, nullptr, nullptr, nullptr, nullptr,
      bn_gamma, bn_beta, bn_mean, bn_var, nullptr, CNT, IDX, H);

  // --- 6 message-passing steps, q/k/v chains fused as 24 mats ---
  for (int s = 0; s < 6; s++) {
    int i = s >> 1;
    const u16* Wq_s = WSZ + (size_t)(1 + i) * 65536;
    const u16* Wk_s = WSZ + (size_t)(4 + i) * 65536;
    const u16* Wv_s = WSZ + (size_t)(7 + i) * 65536;
    const float* bq = bq_mp + i * 256;
    const float* bk = bk_mp + i * 256;
    const float* bv = bv_mp + i * 256;
    const float* inp = (s == 0) ? H : ((s & 1) ? PING : PONG);
    float* oup = (s & 1) ? PONG : PING;
    if (s == 0)
      gemm_k<F_AGG | F_BIAS | F_SILU | F_ASHARED, 3><<<3072, 256, 0, stream>>>(
          H, Wq_s, Wk_s, Wv_s, WLO, bq, bk, bv, nullptr, nullptr,
          bn_gamma, bn_beta, bn_mean, bn_var, nullptr, CNT, IDX, oup);
    else if (s < 5)
      gemm_k<F_AGG | F_BIAS | F_SILU, 3><<<3072, 256, 0, stream>>>(
          inp, Wq_s, Wk_s, Wv_s, WLO, bq, bk, bv, nullptr, nullptr,
          bn_gamma, bn_beta, bn_mean, bn_var, nullptr, CNT, IDX, oup);
    else
      gemm_k<F_AGG | F_BIAS | F_SILU | F_MASKPOST, 3><<<3072, 256, 0, stream>>>(
          inp, Wq_s, Wk_s, Wv_s, WLO, bq, bk, bv, mask, nullptr,
          bn_gamma, bn_beta, bn_mean, bn_var, nullptr, CNT, IDX, oup);
  }
  // finals: q = PONG[0:8), k = PONG[8:16), v = PONG[16:24)

  // --- attention projections ---
  // pq = q @ Wq_att (fp32 out)
  gemm_k<0u, 1><<<1024, 256, 0, stream>>>(
      PONG, WSZ + (size_t)12 * 65536, nullptr, nullptr, WLO,
      nullptr, nullptr, nullptr, nullptr, nullptr,
      bn_gamma, bn_beta, bn_mean, bn_var, nullptr, CNT, IDX, PQ);
  // pk = silu((k @ Wk_att) * m) -> transposed hi/lo planes
  gemm_k<F_SILU | F_MASKPRE | F_TPLANES, 1><<<1024, 256, 0, stream>>>(
      PONG + 8 * MSZ, WSZ + (size_t)10 * 65536, nullptr, nullptr, WLO,
      nullptr, nullptr, nullptr, mask, nullptr,
      bn_gamma, bn_beta, bn_mean, bn_var, nullptr, CNT, IDX, PKT);
  // pv = (v @ Wv_att) * m -> transposed hi/lo planes
  gemm_k<F_MASKPOST | F_TPLANES, 1><<<1024, 256, 0, stream>>>(
      PONG + 16 * MSZ, WSZ + (size_t)11 * 65536, nullptr, nullptr, WLO,
      nullptr, nullptr, nullptr, mask, nullptr,
      bn_gamma, bn_beta, bn_mean, bn_var, nullptr, CNT, IDX, PVT);

  // --- kv = pk^T pv (split-K=8 partials, then reduce + hi/lo swizzle) ---
  kv_k<<<dim3(2, 2, 64), 256, 0, stream>>>(PKT, PVT, KVP);
  kv_conv_k<<<256, 256, 0, stream>>>(KVP, KVS);

  // --- attn = pq @ kv ---
  gemm_k<F_BPERMAT, 1><<<1024, 256, 0, stream>>>(
      PQ, KVS, nullptr, nullptr, KLO,
      nullptr, nullptr, nullptr, nullptr, nullptr,
      bn_gamma, bn_beta, bn_mean, bn_var, nullptr, CNT, IDX, ATTN1);

  // --- y = BN(attn @ Wo + x) ---
  gemm_k<F_ADDX | F_BN, 1><<<1024, 256, 0, stream>>>(
      ATTN1, WSZ + (size_t)13 * 65536, nullptr, nullptr, WLO,
      nullptr, nullptr, nullptr, nullptr, x,
      bn_gamma, bn_beta, bn_mean, bn_var, nullptr, CNT, IDX, Y);

  // --- tmp = x @ W_res + b_res  (PVT region; pk/pv dead after kv_k) ---
  gemm_k<F_BIAS, 1><<<1024, 256, 0, stream>>>(
      x, WSZ + (size_t)15 * 65536, nullptr, nullptr, WLO,
      b_res, nullptr, nullptr, nullptr, nullptr,
      bn_gamma, bn_beta, bn_mean, bn_var, nullptr, CNT, IDX, TMP);

  // --- out = (silu(y @ W_proj + b_proj) + tmp) * mask ---
  gemm_k<F_BIAS | F_SILU | F_ADDT | F_MASKPOST, 1><<<1024, 256, 0, stream>>>(
      Y, WSZ + (size_t)14 * 65536, nullptr, nullptr, WLO,
      b_proj, nullptr, nullptr, mask, nullptr,
      bn_gamma, bn_beta, bn_mean, bn_var, TMP, CNT, IDX, (float*)d_out);

  (void)in_sizes; (void)n_in; (void)out_size; (void)ws_size;
}

// Round 6
// 855.738 us; speedup vs baseline: 1.6127x; 1.6127x over previous
//
#include <hip/hip_runtime.h>
#include <stdint.h>

#define NB 8
#define NN 2048
#define NU 256
#define CAP 64
#define BNEPS 0.001f

typedef __attribute__((ext_vector_type(8))) short short8;
typedef __attribute__((ext_vector_type(4))) float floatx4;
typedef unsigned short u16;
typedef unsigned int u32;

__device__ __forceinline__ float bf2f(u16 u) {
  union { u32 i; float f; } c; c.i = ((u32)u) << 16; return c.f;
}
__device__ __forceinline__ u16 f2bf(float f) {
  union { float f; u32 i; } c; c.f = f;
  return (u16)((c.i + 0x7fffu + ((c.i >> 16) & 1u)) >> 16);
}
// bf16 hi/lo split: a = bf2f(h) + bf2f(l) + O(2^-18 |a|)
__device__ __forceinline__ void splitbf(float a, u16& h, u16& l) {
  h = f2bf(a);
  l = f2bf(a - bf2f(h));
}

enum : unsigned {
  F_BIAS = 2u, F_SILU = 4u, F_MASKPRE = 8u, F_MASKPOST = 16u,
  F_ADDX = 32u, F_BN = 64u, F_ADDT = 128u, F_ASHARED = 256u, F_BPERMAT = 512u,
  F_TPLANES = 1024u
};

#define TP_MAT 524288   // per-batch transposed plane: 256 cols x 2048 rows (u16)
#define TP_LO  4194304  // lo plane offset (u16 elems)
#define MSZ ((size_t)NN * NU)

// ---------------------------------------------------------------------------
// Neighbor-list build: one block per (b, m) row of adj; values are exactly 0/1.
// ---------------------------------------------------------------------------
__global__ __launch_bounds__(256) void build_nbr_k(
    const float* __restrict__ adj, int* __restrict__ cnt, int* __restrict__ idx)
{
  int row = blockIdx.x;  // b*NN + m
  const float* base = adj + (size_t)row * NN;
  __shared__ int c;
  if (threadIdx.x == 0) c = 0;
  __syncthreads();
#pragma unroll
  for (int j = 0; j < 8; j++) {
    int n = j * 256 + threadIdx.x;  // coalesced
    if (base[n] != 0.f) {
      int p = atomicAdd(&c, 1);
      if (p < CAP) idx[(size_t)row * CAP + p] = n;
    }
  }
  __syncthreads();
  if (threadIdx.x == 0) cnt[row] = (c < CAP ? c : CAP);
}

// ---------------------------------------------------------------------------
// Weight conversion: f32 [K=256][N=256] -> TWO bf16 swizzled-B^T planes
// (hi plane [16 mats], then lo plane [16 mats], each mat 65536 u16):
// dst[kb][n][slot][j] = part(W[kb*32 + qv*8 + j][n]), qv = (slot - (n>>1)) & 3
// GEMM reads lane fragment directly from global at n*32 + ((q+(n>>1))&3)*8.
// ---------------------------------------------------------------------------
struct WPtrs { const float* p[16]; };

__global__ __launch_bounds__(256) void conv_w_k(WPtrs wp, u16* __restrict__ dst)
{
  int gid = blockIdx.x * 256 + threadIdx.x;  // 16 mats * 8192 chunks
  int mat = gid >> 13;
  int rem = gid & 8191;
  int kb = rem >> 10;
  int n = (rem >> 2) & 255;
  int slot = rem & 3;
  int qv = (slot - (n >> 1)) & 3;
  int k0 = kb * 32 + qv * 8;
  const float* W = wp.p[mat];
  u32 oh[4], ol[4];
#pragma unroll
  for (int t2 = 0; t2 < 4; t2++) {
    float f0 = W[(size_t)(k0 + 2 * t2) * 256 + n];
    float f1 = W[(size_t)(k0 + 2 * t2 + 1) * 256 + n];
    u16 h0, l0, h1, l1;
    splitbf(f0, h0, l0);
    splitbf(f1, h1, l1);
    oh[t2] = (u32)h0 | ((u32)h1 << 16);
    ol[t2] = (u32)l0 | ((u32)l1 << 16);
  }
  uint4 qh; qh.x = oh[0]; qh.y = oh[1]; qh.z = oh[2]; qh.w = oh[3];
  uint4 ql; ql.x = ol[0]; ql.y = ol[1]; ql.z = ol[2]; ql.w = ol[3];
  *(uint4*)(dst + (size_t)gid * 8) = qh;
  *(uint4*)(dst + 1048576 + (size_t)gid * 8) = ql;  // lo plane at +16*65536
}

// ---------------------------------------------------------------------------
// Dense GEMM, fp32-emulated via bf16 hi/lo 3-term MFMA (round-3 structure).
// Tile: 32 rows x 256 cols, 256 thr (4 waves x 64 cols).
// A (fp32) staged+split in LDS (pitch 264, +16B pad) -> 33.8 KB -> 4 blocks/CU.
// B fragments read per-lane DIRECTLY from swizzled global planes (L2-hot):
// barrier-free K-loop. Grid 1-D 512*NG, XCD-swizzled: xcd = id&7.
// ---------------------------------------------------------------------------
template <unsigned F, int NG>
__global__ __launch_bounds__(256, 4) void gemm_k(
    const float* __restrict__ Abase,
    const u16* __restrict__ W0, const u16* __restrict__ W1, const u16* __restrict__ W2,
    size_t loOff,
    const float* __restrict__ b0, const float* __restrict__ b1, const float* __restrict__ b2,
    const float* __restrict__ mask,
    const float* __restrict__ xf32,
    const float* __restrict__ gma, const float* __restrict__ bta,
    const float* __restrict__ bmu, const float* __restrict__ bvr,
    const float* __restrict__ addt,
    void* __restrict__ outp)
{
  const int tid = threadIdx.x;
  const int id = blockIdx.x;
  const int xcd = id & 7;
  const int t = id >> 3;
  const int chain = (NG == 1) ? 0 : (t % NG);
  const int xt = (NG == 1) ? t : (t / NG);
  const int mat = chain * 8 + xcd;
  const int b = xcd;
  const int bm = xt * 32;

  __shared__ alignas(16) u16 Ah[32 * 264];  // 16896 B
  __shared__ alignas(16) u16 Al[32 * 264];  // 16896 B -> 33792 B total

  const u16* Whi = (F & F_BPERMAT) ? (W0 + (size_t)mat * 65536)
                                   : (chain == 0 ? W0 : (chain == 1 ? W1 : W2));
  const u16* Wlo = Whi + loOff;
  const float* bsel = (chain == 0 ? b0 : (chain == 1 ? b1 : b2));
  const float* Asrc = Abase + ((F & F_ASHARED) ? (size_t)b : (size_t)mat) * MSZ;

  // ---- stage A tile (32 x 256), fp32 -> hi/lo bf16 ----
  for (int s = tid; s < 512; s += 256) {
    int r = s >> 4;
    int c = (s & 15) << 4;
    const float4* fp = (const float4*)(Asrc + (size_t)(bm + r) * NU + c);
    float4 a0 = fp[0], a1 = fp[1], a2 = fp[2], a3 = fp[3];
    float vv[16] = {a0.x, a0.y, a0.z, a0.w, a1.x, a1.y, a1.z, a1.w,
                    a2.x, a2.y, a2.z, a2.w, a3.x, a3.y, a3.z, a3.w};
    u32 hh[8], ll[8];
#pragma unroll
    for (int j = 0; j < 8; j++) {
      u16 h0, l0, h1, l1;
      splitbf(vv[2 * j], h0, l0);
      splitbf(vv[2 * j + 1], h1, l1);
      hh[j] = (u32)h0 | ((u32)h1 << 16);
      ll[j] = (u32)l0 | ((u32)l1 << 16);
    }
    uint4 H0; H0.x = hh[0]; H0.y = hh[1]; H0.z = hh[2]; H0.w = hh[3];
    uint4 H1; H1.x = hh[4]; H1.y = hh[5]; H1.z = hh[6]; H1.w = hh[7];
    uint4 L0; L0.x = ll[0]; L0.y = ll[1]; L0.z = ll[2]; L0.w = ll[3];
    uint4 L1; L1.x = ll[4]; L1.y = ll[5]; L1.z = ll[6]; L1.w = ll[7];
    *(uint4*)&Ah[r * 264 + c] = H0;
    *(uint4*)&Ah[r * 264 + c + 8] = H1;
    *(uint4*)&Al[r * 264 + c] = L0;
    *(uint4*)&Al[r * 264 + c + 8] = L1;
  }
  __syncthreads();

  const int lane = tid & 63;
  const int w = tid >> 6;
  const int m16 = lane & 15;
  const int q = lane >> 4;

  floatx4 acc[2][4];
#pragma unroll
  for (int i = 0; i < 2; i++)
#pragma unroll
    for (int j = 0; j < 4; j++) acc[i][j] = (floatx4){0.f, 0.f, 0.f, 0.f};

  // barrier-free K-loop: B fragments straight from global (swizzled layout)
#pragma unroll
  for (int kk = 0; kk < 8; kk++) {
    short8 bh[4], bl2[4];
#pragma unroll
    for (int nt = 0; nt < 4; nt++) {
      int n = w * 64 + nt * 16 + m16;
      size_t off = (size_t)kk * 8192 + (size_t)n * 32 + (size_t)(((q + (n >> 1)) & 3) * 8);
      bh[nt] = *(const short8*)(Whi + off);
      bl2[nt] = *(const short8*)(Wlo + off);
    }
#pragma unroll
    for (int mt = 0; mt < 2; mt++) {
      short8 ah = *(const short8*)&Ah[(mt * 16 + m16) * 264 + kk * 32 + q * 8];
      short8 al2 = *(const short8*)&Al[(mt * 16 + m16) * 264 + kk * 32 + q * 8];
#pragma unroll
      for (int nt = 0; nt < 4; nt++) {
        acc[mt][nt] = __builtin_amdgcn_mfma_f32_16x16x32_bf16(ah, bh[nt], acc[mt][nt], 0, 0, 0);
        acc[mt][nt] = __builtin_amdgcn_mfma_f32_16x16x32_bf16(al2, bh[nt], acc[mt][nt], 0, 0, 0);
        acc[mt][nt] = __builtin_amdgcn_mfma_f32_16x16x32_bf16(ah, bl2[nt], acc[mt][nt], 0, 0, 0);
      }
    }
  }

  // ---- epilogue ----
#pragma unroll
  for (int mt = 0; mt < 2; mt++) {
    if (F & F_TPLANES) {
      // transposed bf16 hi/lo planes: oT[col][row], per batch b
      u16* oh = (u16*)outp + (size_t)b * TP_MAT;
      u16* ol = oh + TP_LO;
      int gr0 = bm + mt * 16 + q * 4;
#pragma unroll
      for (int nt = 0; nt < 4; nt++) {
        int col = w * 64 + nt * 16 + m16;
        u16 hh[4], ll[4];
#pragma unroll
        for (int r = 0; r < 4; r++) {
          float t2 = acc[mt][nt][r];
          float mv = mask[b * NN + gr0 + r];
          if (F & F_MASKPRE) t2 *= mv;
          if (F & F_SILU) t2 = t2 / (1.f + __expf(-t2));
          if (F & F_MASKPOST) t2 *= mv;
          splitbf(t2, hh[r], ll[r]);
        }
        uint2 H2, L2v;
        H2.x = (u32)hh[0] | ((u32)hh[1] << 16);
        H2.y = (u32)hh[2] | ((u32)hh[3] << 16);
        L2v.x = (u32)ll[0] | ((u32)ll[1] << 16);
        L2v.y = (u32)ll[2] | ((u32)ll[3] << 16);
        *(uint2*)(oh + (size_t)col * 2048 + gr0) = H2;
        *(uint2*)(ol + (size_t)col * 2048 + gr0) = L2v;
      }
    } else {
      float* outf = (float*)outp;
#pragma unroll
      for (int r = 0; r < 4; r++) {
        int gr = bm + mt * 16 + q * 4 + r;
        float mval = 1.f;
        if (F & (F_MASKPRE | F_MASKPOST)) mval = mask[b * NN + gr];
#pragma unroll
        for (int nt = 0; nt < 4; nt++) {
          int col = w * 64 + nt * 16 + m16;
          float t2 = acc[mt][nt][r];
          if (F & F_BIAS) t2 += bsel[col];
          if (F & F_MASKPRE) t2 *= mval;
          if (F & F_SILU) t2 = t2 / (1.f + __expf(-t2));
          if (F & F_ADDX) t2 += xf32[((size_t)b * NN + gr) * NU + col];
          if (F & F_BN) t2 = gma[col] * (t2 - bmu[col]) * rsqrtf(bvr[col] + BNEPS) + bta[col];
          if (F & F_ADDT) t2 += addt[((size_t)mat * NN + gr) * NU + col];
          if (F & F_MASKPOST) t2 *= mval;
          outf[((size_t)mat * NN + gr) * NU + col] = t2;
        }
      }
    }
  }
}

// ---------------------------------------------------------------------------
// Gather/aggregation kernel: x'[m] = epi( sum_{n in nbr(m)} g[n] + bias ).
// One wave per row (64 lanes x float4 = 256 cols). Per-chain dispatch so each
// XCD's gather source (one 2MB mat) is L2-resident. Grid 4096: b=id&7.
// ---------------------------------------------------------------------------
template <unsigned F>
__global__ __launch_bounds__(256, 8) void agg_k(
    const float* __restrict__ g, float* __restrict__ xo,
    const float* __restrict__ bias, const float* __restrict__ mask,
    const int* __restrict__ ncnt, const int* __restrict__ nidx)
{
  int id = blockIdx.x;
  int b = id & 7;
  int rg = id >> 3;
  int tid = threadIdx.x;
  int w = tid >> 6;
  int l = tid & 63;
  int row = rg * 4 + w;
  int rowid = b * NN + row;
  const float* __restrict__ gm = g + (size_t)b * MSZ;
  int cnt = ncnt[rowid];
  const int* __restrict__ ip = nidx + (size_t)rowid * CAP;
  int c = l * 4;
  float4 a; a.x = a.y = a.z = a.w = 0.f;
  int e = 0;
  for (; e + 4 <= cnt; e += 4) {
    int4 i4 = *(const int4*)(ip + e);
    float4 v0 = *(const float4*)(gm + ((size_t)i4.x << 8) + c);
    float4 v1 = *(const float4*)(gm + ((size_t)i4.y << 8) + c);
    float4 v2 = *(const float4*)(gm + ((size_t)i4.z << 8) + c);
    float4 v3 = *(const float4*)(gm + ((size_t)i4.w << 8) + c);
    a.x += v0.x + v1.x + v2.x + v3.x;
    a.y += v0.y + v1.y + v2.y + v3.y;
    a.z += v0.z + v1.z + v2.z + v3.z;
    a.w += v0.w + v1.w + v2.w + v3.w;
  }
  for (; e < cnt; e++) {
    float4 v = *(const float4*)(gm + ((size_t)ip[e] << 8) + c);
    a.x += v.x; a.y += v.y; a.z += v.z; a.w += v.w;
  }
  float4 bb = *(const float4*)(bias + c);
  float o[4] = {a.x + bb.x, a.y + bb.y, a.z + bb.z, a.w + bb.w};
  float mv = (F & F_MASKPOST) ? mask[rowid] : 1.f;
#pragma unroll
  for (int j = 0; j < 4; j++) {
    float t = o[j];
    if (F & F_SILU) t = t / (1.f + __expf(-t));
    if (F & F_MASKPOST) t *= mv;
    o[j] = t;
  }
  float4 ov; ov.x = o[0]; ov.y = o[1]; ov.z = o[2]; ov.w = o[3];
  *(float4*)(xo + (size_t)b * MSZ + ((size_t)row << 8) + c) = ov;
}

// ---------------------------------------------------------------------------
// kv[d][e] = sum_n pk[n][d] * pv[n][e], from transposed bf16 hi/lo planes.
// LDS-free, 3-term. Split-K=8: part[z = p*8+b][d][e], grid (2,2,64).
// ---------------------------------------------------------------------------
__global__ __launch_bounds__(256, 2) void kv_k(
    const u16* __restrict__ pkT, const u16* __restrict__ pvT, float* __restrict__ part)
{
  int et = blockIdx.x * 128;
  int dt = blockIdx.y * 128;
  int z = blockIdx.z;
  int b = z & 7;
  int p = z >> 3;
  int tid = threadIdx.x;
  int lane = tid & 63, w = tid >> 6;
  int m16 = lane & 15, q = lane >> 4;

  const u16* pkh = pkT + (size_t)b * TP_MAT;
  const u16* pkl = pkh + TP_LO;
  const u16* pvh = pvT + (size_t)b * TP_MAT;
  const u16* pvl = pvh + TP_LO;

  int d_base = dt + (w >> 1) * 64 + m16;
  int e_base = et + (w & 1) * 64 + m16;

  floatx4 acc[4][4];
#pragma unroll
  for (int i = 0; i < 4; i++)
#pragma unroll
    for (int j = 0; j < 4; j++) acc[i][j] = (floatx4){0.f, 0.f, 0.f, 0.f};

#pragma unroll
  for (int kt = 0; kt < 8; kt++) {
    int kc = p * 256 + kt * 32 + q * 8;
    short8 ah[4], al[4], bh[4], bl[4];
#pragma unroll
    for (int mt = 0; mt < 4; mt++) {
      size_t o = (size_t)(d_base + mt * 16) * 2048 + kc;
      ah[mt] = *(const short8*)(pkh + o);
      al[mt] = *(const short8*)(pkl + o);
    }
#pragma unroll
    for (int nt = 0; nt < 4; nt++) {
      size_t o = (size_t)(e_base + nt * 16) * 2048 + kc;
      bh[nt] = *(const short8*)(pvh + o);
      bl[nt] = *(const short8*)(pvl + o);
    }
#pragma unroll
    for (int mt = 0; mt < 4; mt++)
#pragma unroll
      for (int nt = 0; nt < 4; nt++) {
        acc[mt][nt] = __builtin_amdgcn_mfma_f32_16x16x32_bf16(ah[mt], bh[nt], acc[mt][nt], 0, 0, 0);
        acc[mt][nt] = __builtin_amdgcn_mfma_f32_16x16x32_bf16(al[mt], bh[nt], acc[mt][nt], 0, 0, 0);
        acc[mt][nt] = __builtin_amdgcn_mfma_f32_16x16x32_bf16(ah[mt], bl[nt], acc[mt][nt], 0, 0, 0);
      }
  }

#pragma unroll
  for (int mt = 0; mt < 4; mt++)
#pragma unroll
    for (int r = 0; r < 4; r++) {
      int d = dt + (w >> 1) * 64 + mt * 16 + q * 4 + r;
#pragma unroll
      for (int nt = 0; nt < 4; nt++) {
        int e = et + (w & 1) * 64 + nt * 16 + m16;
        part[(size_t)z * 65536 + (size_t)d * 256 + e] = acc[mt][nt][r];
      }
    }
}

// Reduce split-K partials (8 p-planes) and emit kv bf16 hi/lo swizzled planes.
__global__ __launch_bounds__(256) void kv_conv_k(const float* __restrict__ part, u16* __restrict__ dst)
{
  int gid = blockIdx.x * 256 + threadIdx.x;  // 8 * 8192 = 65536
  int b = gid >> 13;
  int rem = gid & 8191;
  int kb = rem >> 10;
  int e = (rem >> 2) & 255;
  int slot = rem & 3;
  int qv = (slot - (e >> 1)) & 3;
  int d0 = kb * 32 + qv * 8;
  const float* src = part + (size_t)b * 65536 + (size_t)d0 * 256 + e;
  u32 oh[4], ol[4];
#pragma unroll
  for (int t2 = 0; t2 < 4; t2++) {
    float s0 = 0.f, s1 = 0.f;
#pragma unroll
    for (int pp = 0; pp < 8; pp++) {
      const float* sp = src + (size_t)pp * 524288 + t2 * 512;
      s0 += sp[0];
      s1 += sp[256];
    }
    u16 h0, l0, h1, l1;
    splitbf(s0, h0, l0);
    splitbf(s1, h1, l1);
    oh[t2] = (u32)h0 | ((u32)h1 << 16);
    ol[t2] = (u32)l0 | ((u32)l1 << 16);
  }
  uint4 qh; qh.x = oh[0]; qh.y = oh[1]; qh.z = oh[2]; qh.w = oh[3];
  uint4 ql; ql.x = ol[0]; ql.y = ol[1]; ql.z = ol[2]; ql.w = ol[3];
  *(uint4*)(dst + (size_t)gid * 8) = qh;
  *(uint4*)(dst + 524288 + (size_t)gid * 8) = ql;  // lo plane at +8*65536
}

// ---------------------------------------------------------------------------
extern "C" void kernel_launch(void* const* d_in, const int* in_sizes, int n_in,
                              void* d_out, int out_size, void* d_ws, size_t ws_size,
                              hipStream_t stream)
{
  const float* x = (const float*)d_in[0];
  const float* adj = (const float*)d_in[1];
  const float* mask = (const float*)d_in[2];
  const float* W_lin = (const float*)d_in[3];
  const float* b_lin = (const float*)d_in[4];
  const float* Wq_mp = (const float*)d_in[5];
  const float* bq_mp = (const float*)d_in[6];
  const float* Wk_mp = (const float*)d_in[7];
  const float* bk_mp = (const float*)d_in[8];
  const float* Wv_mp = (const float*)d_in[9];
  const float* bv_mp = (const float*)d_in[10];
  const float* Wk_att = (const float*)d_in[11];
  const float* Wv_att = (const float*)d_in[12];
  const float* Wq_att = (const float*)d_in[13];
  const float* Wo_att = (const float*)d_in[14];
  const float* bn_gamma = (const float*)d_in[15];
  const float* bn_beta = (const float*)d_in[16];
  const float* bn_mean = (const float*)d_in[17];
  const float* bn_var = (const float*)d_in[18];
  const float* W_proj = (const float*)d_in[19];
  const float* b_proj = (const float*)d_in[20];
  const float* W_res = (const float*)d_in[21];
  const float* b_res = (const float*)d_in[22];

  char* ws = (char*)d_ws;
  int* CNT    = (int*)(ws + 0);               // 64 KB
  int* IDX    = (int*)(ws + (1ull << 20));    // 4 MB
  u16* WSZ    = (u16*)(ws + (5ull << 20));    // 4 MB (bf16 hi 2MB + lo 2MB)
  u16* KVS    = (u16*)(ws + (9ull << 20));    // 2 MB (bf16 hi 1MB + lo 1MB)
  float* KVP  = (float*)(ws + (11ull << 20)); // 16 MB
  float* B0   = (float*)(ws + (27ull << 20)); // 48 MB
  float* B1   = (float*)(ws + (75ull << 20)); // 48 MB
  float* B2   = (float*)(ws + (123ull << 20));// 48 MB  (total 171 MB)

  const size_t WLO = 1048576;  // weight lo-plane offset (u16 elems)
  const size_t KLO = 524288;   // kv lo-plane offset
  float* H = B2;                               // 16 MB (8 mats), dead after step-0 A
  float* bufs[3] = {B0, B1, B2};
  // rotation: in = {2,1,0,2,1,0}[s], g = {0,2,1,0,2,1}[s], out = {1,0,2,1,0,2}[s]
  const int inI[6] = {2, 1, 0, 2, 1, 0};
  const int gI[6]  = {0, 2, 1, 0, 2, 1};
  const int oI[6]  = {1, 0, 2, 1, 0, 2};

  float* PQ = B0;                              // 16 MB fp32
  u16* PKT = (u16*)((char*)B0 + (16ull << 20));// 16 MB (hi 8 + lo 8)
  u16* PVT = (u16*)((char*)B0 + (32ull << 20));// 16 MB
  float* ATTN1 = B1;                           // 16 MB
  float* Y = (float*)((char*)B1 + (16ull << 20));
  float* TMP = (float*)((char*)B1 + (32ull << 20));

  // --- conversions + neighbor lists ---
  WPtrs wp;
  wp.p[0] = W_lin;
  wp.p[1] = Wq_mp; wp.p[2] = Wq_mp + 65536; wp.p[3] = Wq_mp + 131072;
  wp.p[4] = Wk_mp; wp.p[5] = Wk_mp + 65536; wp.p[6] = Wk_mp + 131072;
  wp.p[7] = Wv_mp; wp.p[8] = Wv_mp + 65536; wp.p[9] = Wv_mp + 131072;
  wp.p[10] = Wk_att; wp.p[11] = Wv_att; wp.p[12] = Wq_att; wp.p[13] = Wo_att;
  wp.p[14] = W_proj; wp.p[15] = W_res;
  conv_w_k<<<512, 256, 0, stream>>>(wp, WSZ);
  build_nbr_k<<<NB * NN, 256, 0, stream>>>(adj, CNT, IDX);

  // --- h = x @ W_lin + b_lin ---
  gemm_k<F_BIAS, 1><<<512, 256, 0, stream>>>(x, WSZ, nullptr, nullptr, WLO,
      b_lin, nullptr, nullptr, nullptr, nullptr,
      bn_gamma, bn_beta, bn_mean, bn_var, nullptr, H);

  // --- 6 message-passing steps via associativity: g = x@W, then x' = silu(adj@g + b) ---
  for (int s = 0; s < 6; s++) {
    int i = s >> 1;
    const u16* Wq_s = WSZ + (size_t)(1 + i) * 65536;
    const u16* Wk_s = WSZ + (size_t)(4 + i) * 65536;
    const u16* Wv_s = WSZ + (size_t)(7 + i) * 65536;
    float* inb = bufs[inI[s]];
    float* gb = bufs[gI[s]];
    float* ob = bufs[oI[s]];
    // A: dense GEMM, 24 mats (chains q/k/v)
    if (s == 0)
      gemm_k<F_ASHARED, 3><<<1536, 256, 0, stream>>>(H, Wq_s, Wk_s, Wv_s, WLO,
          nullptr, nullptr, nullptr, nullptr, nullptr,
          bn_gamma, bn_beta, bn_mean, bn_var, nullptr, gb);
    else
      gemm_k<0u, 3><<<1536, 256, 0, stream>>>(inb, Wq_s, Wk_s, Wv_s, WLO,
          nullptr, nullptr, nullptr, nullptr, nullptr,
          bn_gamma, bn_beta, bn_mean, bn_var, nullptr, gb);
    // B: per-chain gather (+bias+silu, +mask on last step) — L2-resident source
    const float* biases[3] = {bq_mp + i * 256, bk_mp + i * 256, bv_mp + i * 256};
    for (int c = 0; c < 3; c++) {
      const float* gsrc = gb + (size_t)c * 8 * MSZ;
      float* xdst = ob + (size_t)c * 8 * MSZ;
      if (s == 5)
        agg_k<F_BIAS | F_SILU | F_MASKPOST><<<4096, 256, 0, stream>>>(
            gsrc, xdst, biases[c], mask, CNT, IDX);
      else
        agg_k<F_BIAS | F_SILU><<<4096, 256, 0, stream>>>(
            gsrc, xdst, biases[c], mask, CNT, IDX);
    }
  }
  // finals (fp32): q = B2[0:8), k = B2[8:16), v = B2[16:24)
  float* QF = B2;
  float* KF = B2 + 8 * MSZ;
  float* VF = B2 + 16 * MSZ;

  // --- attention projections ---
  gemm_k<0u, 1><<<512, 256, 0, stream>>>(
      QF, WSZ + (size_t)12 * 65536, nullptr, nullptr, WLO,
      nullptr, nullptr, nullptr, nullptr, nullptr,
      bn_gamma, bn_beta, bn_mean, bn_var, nullptr, PQ);
  gemm_k<F_SILU | F_MASKPRE | F_TPLANES, 1><<<512, 256, 0, stream>>>(
      KF, WSZ + (size_t)10 * 65536, nullptr, nullptr, WLO,
      nullptr, nullptr, nullptr, mask, nullptr,
      bn_gamma, bn_beta, bn_mean, bn_var, nullptr, PKT);
  gemm_k<F_MASKPOST | F_TPLANES, 1><<<512, 256, 0, stream>>>(
      VF, WSZ + (size_t)11 * 65536, nullptr, nullptr, WLO,
      nullptr, nullptr, nullptr, mask, nullptr,
      bn_gamma, bn_beta, bn_mean, bn_var, nullptr, PVT);

  // --- kv = pk^T pv (split-K=8 partials, then reduce + hi/lo swizzle) ---
  kv_k<<<dim3(2, 2, 64), 256, 0, stream>>>(PKT, PVT, KVP);
  kv_conv_k<<<256, 256, 0, stream>>>(KVP, KVS);

  // --- attn = pq @ kv ---
  gemm_k<F_BPERMAT, 1><<<512, 256, 0, stream>>>(
      PQ, KVS, nullptr, nullptr, KLO,
      nullptr, nullptr, nullptr, nullptr, nullptr,
      bn_gamma, bn_beta, bn_mean, bn_var, nullptr, ATTN1);

  // --- y = BN(attn @ Wo + x) ---
  gemm_k<F_ADDX | F_BN, 1><<<512, 256, 0, stream>>>(
      ATTN1, WSZ + (size_t)13 * 65536, nullptr, nullptr, WLO,
      nullptr, nullptr, nullptr, nullptr, x,
      bn_gamma, bn_beta, bn_mean, bn_var, nullptr, Y);

  // --- tmp = x @ W_res + b_res ---
  gemm_k<F_BIAS, 1><<<512, 256, 0, stream>>>(
      x, WSZ + (size_t)15 * 65536, nullptr, nullptr, WLO,
      b_res, nullptr, nullptr, nullptr, nullptr,
      bn_gamma, bn_beta, bn_mean, bn_var, nullptr, TMP);

  // --- out = (silu(y @ W_proj + b_proj) + tmp) * mask ---
  gemm_k<F_BIAS | F_SILU | F_ADDT | F_MASKPOST, 1><<<512, 256, 0, stream>>>(
      Y, WSZ + (size_t)14 * 65536, nullptr, nullptr, WLO,
      b_proj, nullptr, nullptr, mask, nullptr,
      bn_gamma, bn_beta, bn_mean, bn_var, TMP, d_out);

  (void)in_sizes; (void)n_in; (void)out_size; (void)ws_size;
}